// Round 3
// baseline (827.477 us; speedup 1.0000x reference)
//
#include <hip/hip_runtime.h>

#define Nn 4096
#define Cc 256
#define NN2 ((size_t)Nn * Nn)

typedef __attribute__((ext_vector_type(8))) short bf16x8;
typedef __attribute__((ext_vector_type(4))) float f32x4;

__device__ __forceinline__ unsigned short f2bf(float f) {
    union { float f; unsigned u; } v; v.f = f;
    unsigned r = v.u + 0x7FFF + ((v.u >> 16) & 1);
    return (unsigned short)(r >> 16);
}

__device__ __forceinline__ bf16x8 pack2(const float4& a, const float4& b) {
    bf16x8 o;
    o[0] = (short)f2bf(a.x); o[1] = (short)f2bf(a.y);
    o[2] = (short)f2bf(a.z); o[3] = (short)f2bf(a.w);
    o[4] = (short)f2bf(b.x); o[5] = (short)f2bf(b.y);
    o[6] = (short)f2bf(b.z); o[7] = (short)f2bf(b.w);
    return o;
}

// exp 8 floats (two float4), accumulate sum into sacc, return packed bf16x8
__device__ __forceinline__ bf16x8 exp8acc(const float4 a, const float4 b, float& sacc) {
    const float s0 = __expf(a.x), s1 = __expf(a.y), s2 = __expf(a.z), s3 = __expf(a.w);
    const float s4 = __expf(b.x), s5 = __expf(b.y), s6 = __expf(b.z), s7 = __expf(b.w);
    sacc += ((s0 + s1) + (s2 + s3)) + ((s4 + s5) + (s6 + s7));
    bf16x8 o;
    o[0] = (short)f2bf(s0); o[1] = (short)f2bf(s1);
    o[2] = (short)f2bf(s2); o[3] = (short)f2bf(s3);
    o[4] = (short)f2bf(s4); o[5] = (short)f2bf(s5);
    o[6] = (short)f2bf(s6); o[7] = (short)f2bf(s7);
    return o;
}

// ---------------------------------------------------------------------------
// Kernel 1: V[b,o,n] = bf16( sum_c W[o,c]*X[b,c,n] + bias[o] )
// (unchanged from round 2 — not the bottleneck)
// ---------------------------------------------------------------------------
__global__ __launch_bounds__(256) void value_gemm(
    const float* __restrict__ X, const float* __restrict__ W,
    const float* __restrict__ bias, unsigned short* __restrict__ Vout)
{
    __shared__ float Xs[256][33];   // [k][n] tile, +1 pad on 32

    const int t = threadIdx.x;
    const int b  = blockIdx.x >> 7;
    const int n0 = (blockIdx.x & 127) << 5;
    const int wave = t >> 6, lane = t & 63;
    const int lrow = lane & 15, lq = lane >> 4;

    const float* Xb = X + (size_t)b * Cc * Nn + n0;

    {
        const int r0 = t >> 3, c4 = (t & 7) << 2;
        #pragma unroll
        for (int i = 0; i < 8; ++i) {
            const int r = r0 + i * 32;
            const float4 v = *(const float4*)(Xb + (size_t)r * Nn + c4);
            Xs[r][c4 + 0] = v.x; Xs[r][c4 + 1] = v.y;
            Xs[r][c4 + 2] = v.z; Xs[r][c4 + 3] = v.w;
        }
    }
    __syncthreads();

    f32x4 acc[4][2] = {};

    #pragma unroll 2
    for (int k0 = 0; k0 < Cc; k0 += 32) {
        bf16x8 af[4];
        #pragma unroll
        for (int ci = 0; ci < 4; ++ci) {
            const float* wp = W + (size_t)(wave * 64 + ci * 16 + lrow) * Cc + k0 + lq * 8;
            af[ci] = pack2(*(const float4*)wp, *(const float4*)(wp + 4));
        }
        bf16x8 bp[2];
        #pragma unroll
        for (int mi = 0; mi < 2; ++mi) {
            const int n = mi * 16 + lrow;
            bf16x8 o;
            #pragma unroll
            for (int j = 0; j < 8; ++j) o[j] = (short)f2bf(Xs[k0 + lq * 8 + j][n]);
            bp[mi] = o;
        }
        #pragma unroll
        for (int ci = 0; ci < 4; ++ci)
            #pragma unroll
            for (int mi = 0; mi < 2; ++mi)
                acc[ci][mi] = __builtin_amdgcn_mfma_f32_16x16x32_bf16(
                    af[ci], bp[mi], acc[ci][mi], 0, 0, 0);
    }

    #pragma unroll
    for (int ci = 0; ci < 4; ++ci) {
        #pragma unroll
        for (int rr = 0; rr < 4; ++rr) {
            const int o = wave * 64 + ci * 16 + lq * 4 + rr;
            const float bo = bias[o];
            #pragma unroll
            for (int mi = 0; mi < 2; ++mi) {
                const int n = n0 + mi * 16 + lrow;
                Vout[((size_t)(b * Cc + o)) * Nn + n] = f2bf(acc[ci][mi][rr] + bo);
            }
        }
    }
}

// ---------------------------------------------------------------------------
// Kernel 2 v3: BARRIER-FREE, LDS-FREE.
// Each wave owns (c=64, m=32): loads its 16 E floats/lane/step to registers,
// exp+packs in-register (B-frag), MFMAs against register V frags.
// Block = 4 waves = 4 c-quarters of one (b, m-tile): same-CU waves reuse the
// same E lines via L1/L2. Grid 512 = 4b x 128 m-tiles; b = blk&3 pins batch
// to XCDs {b, b+4} for V L2 residency. Softmax denom = lane-local exp sums
// reduced over the 4 lq groups (shfl_xor 16/32). Zero __syncthreads.
// Double-buffered (A/B) register prefetch at distance 2 half-steps.
// ---------------------------------------------------------------------------
__global__ __launch_bounds__(256, 2) void attn_gemm(
    const unsigned short* __restrict__ V, const float* __restrict__ E,
    const float* __restrict__ X, const float* __restrict__ gamma,
    float* __restrict__ Out)
{
    const int t = threadIdx.x;
    const int wave = t >> 6, lane = t & 63;
    const int lrow = lane & 15, lq = lane >> 4;
    const int blk = blockIdx.x;
    const int b  = blk & 3;
    const int m0 = (blk >> 2) << 5;   // 32-row m-tile
    const int c0 = wave << 6;         // c-quarter

    // E row pointers for this lane's two m-rows (mi=0: lrow, mi=1: lrow+16)
    const float* ep0 = E + (size_t)b * NN2 + (size_t)(m0 + lrow) * Nn + lq * 8;
    const float* ep1 = ep0 + (size_t)16 * Nn;

    // V fragment addressing: rows c0+ci*16+lrow, cols lq*8 (+ k*64 + kk*32)
    const unsigned short* vbase = V + (size_t)(b * Cc + c0) * Nn;
    int voff[4];
    #pragma unroll
    for (int ci = 0; ci < 4; ++ci) voff[ci] = (ci * 16 + lrow) * Nn + lq * 8;

    f32x4 acc[4][2] = {};            // [ci][mi]
    float sacc0 = 0.f, sacc1 = 0.f;  // per-lane exp sums for rows mi=0 / mi=1

    // E regs: [mi*4 + kk*2 + h] (h = float4 half); V regs: [kk*4 + ci]
    float4 eA[8], eB[8];
    bf16x8 vA[8], vB[8];

    // ---- prologue: load k=0 into A, k=1 into B ----
    #pragma unroll
    for (int kk = 0; kk < 2; ++kk) {
        eA[0 + kk * 2 + 0] = *(const float4*)(ep0 + kk * 32);
        eA[0 + kk * 2 + 1] = *(const float4*)(ep0 + kk * 32 + 4);
        eA[4 + kk * 2 + 0] = *(const float4*)(ep1 + kk * 32);
        eA[4 + kk * 2 + 1] = *(const float4*)(ep1 + kk * 32 + 4);
        eB[0 + kk * 2 + 0] = *(const float4*)(ep0 + 64 + kk * 32);
        eB[0 + kk * 2 + 1] = *(const float4*)(ep0 + 64 + kk * 32 + 4);
        eB[4 + kk * 2 + 0] = *(const float4*)(ep1 + 64 + kk * 32);
        eB[4 + kk * 2 + 1] = *(const float4*)(ep1 + 64 + kk * 32 + 4);
    }
    #pragma unroll
    for (int kk = 0; kk < 2; ++kk)
        #pragma unroll
        for (int ci = 0; ci < 4; ++ci) {
            vA[kk * 4 + ci] = *(const bf16x8*)(vbase + voff[ci] + kk * 32);
            vB[kk * 4 + ci] = *(const bf16x8*)(vbase + voff[ci] + 64 + kk * 32);
        }

    // half-step: consume E/V set, prefetch same set for ks+2
#define HALF(Ee, Vv, ks)                                                      \
    {                                                                          \
        bf16x8 bfr00 = exp8acc(Ee[0], Ee[1], sacc0);  /* mi0 kk0 */            \
        bf16x8 bfr01 = exp8acc(Ee[2], Ee[3], sacc0);  /* mi0 kk1 */            \
        bf16x8 bfr10 = exp8acc(Ee[4], Ee[5], sacc1);  /* mi1 kk0 */            \
        bf16x8 bfr11 = exp8acc(Ee[6], Ee[7], sacc1);  /* mi1 kk1 */            \
        const int kc = (((ks) + 2) & 63) << 6;                                 \
        Ee[0] = *(const float4*)(ep0 + kc);                                    \
        Ee[1] = *(const float4*)(ep0 + kc + 4);                                \
        Ee[2] = *(const float4*)(ep0 + kc + 32);                               \
        Ee[3] = *(const float4*)(ep0 + kc + 36);                               \
        Ee[4] = *(const float4*)(ep1 + kc);                                    \
        Ee[5] = *(const float4*)(ep1 + kc + 4);                                \
        Ee[6] = *(const float4*)(ep1 + kc + 32);                               \
        Ee[7] = *(const float4*)(ep1 + kc + 36);                               \
        _Pragma("unroll")                                                      \
        for (int ci = 0; ci < 4; ++ci) {                                       \
            acc[ci][0] = __builtin_amdgcn_mfma_f32_16x16x32_bf16(              \
                Vv[ci], bfr00, acc[ci][0], 0, 0, 0);                           \
            acc[ci][1] = __builtin_amdgcn_mfma_f32_16x16x32_bf16(              \
                Vv[ci], bfr10, acc[ci][1], 0, 0, 0);                           \
        }                                                                      \
        _Pragma("unroll")                                                      \
        for (int ci = 0; ci < 4; ++ci) {                                       \
            acc[ci][0] = __builtin_amdgcn_mfma_f32_16x16x32_bf16(              \
                Vv[4 + ci], bfr01, acc[ci][0], 0, 0, 0);                       \
            acc[ci][1] = __builtin_amdgcn_mfma_f32_16x16x32_bf16(              \
                Vv[4 + ci], bfr11, acc[ci][1], 0, 0, 0);                       \
        }                                                                      \
        _Pragma("unroll")                                                      \
        for (int ci = 0; ci < 4; ++ci) {                                       \
            Vv[ci]     = *(const bf16x8*)(vbase + voff[ci] + kc);              \
            Vv[4 + ci] = *(const bf16x8*)(vbase + voff[ci] + kc + 32);         \
        }                                                                      \
    }

    #pragma unroll 1
    for (int k = 0; k < 64; k += 2) {
        HALF(eA, vA, k);
        HALF(eB, vB, k + 1);
    }
#undef HALF

    // ---- softmax denominators: reduce lane sums over the 4 lq groups ----
    float s0 = sacc0;
    s0 += __shfl_xor(s0, 16);
    s0 += __shfl_xor(s0, 32);
    float s1 = sacc1;
    s1 += __shfl_xor(s1, 16);
    s1 += __shfl_xor(s1, 32);

    // ---- epilogue ----
    const float g = gamma[0];
    const float sc[2] = { g / s0, g / s1 };
    #pragma unroll
    for (int mi = 0; mi < 2; ++mi) {
        const int m = m0 + mi * 16 + lrow;
        #pragma unroll
        for (int ci = 0; ci < 4; ++ci) {
            #pragma unroll
            for (int rr = 0; rr < 4; ++rr) {
                const int c = c0 + ci * 16 + lq * 4 + rr;
                const size_t off = ((size_t)(b * Cc + c)) * Nn + m;
                Out[off] = sc[mi] * acc[ci][mi][rr] + 2.0f * X[off];
            }
        }
    }
}

extern "C" void kernel_launch(void* const* d_in, const int* in_sizes, int n_in,
                              void* d_out, int out_size, void* d_ws, size_t ws_size,
                              hipStream_t stream) {
    const float* energy  = (const float*)d_in[0];  // [4,4096,4096]
    const float* x       = (const float*)d_in[1];  // [4,256,64,64]
    const float* value_w = (const float*)d_in[2];  // [256,256]
    const float* value_b = (const float*)d_in[3];  // [256]
    const float* gamma   = (const float*)d_in[4];  // [1]
    float* out = (float*)d_out;
    unsigned short* Vws = (unsigned short*)d_ws;   // 4*256*4096 bf16 = 8 MB

    value_gemm<<<512, 256, 0, stream>>>(x, value_w, value_b, Vws);
    attn_gemm<<<512, 256, 0, stream>>>(Vws, energy, x, gamma, out);
}

// Round 4
// 455.311 us; speedup vs baseline: 1.8174x; 1.8174x over previous
//
#include <hip/hip_runtime.h>

#define Nn 4096
#define Cc 256
#define NN2 ((size_t)Nn * Nn)

typedef __attribute__((ext_vector_type(8))) short bf16x8;
typedef __attribute__((ext_vector_type(4))) short bf16x4;
typedef __attribute__((ext_vector_type(4))) float f32x4;

// Barrier draining ONLY LDS ops (cross-wave hazard = Bexp double buffer).
// Global register loads stay in flight across it.
#define LDSBAR() do { \
    asm volatile("s_waitcnt lgkmcnt(0)" ::: "memory"); \
    __builtin_amdgcn_s_barrier(); \
} while (0)

__device__ __forceinline__ unsigned short f2bf(float f) {
    union { float f; unsigned u; } v; v.f = f;
    unsigned r = v.u + 0x7FFF + ((v.u >> 16) & 1);
    return (unsigned short)(r >> 16);
}

__device__ __forceinline__ bf16x8 pack2(const float4& a, const float4& b) {
    bf16x8 o;
    o[0] = (short)f2bf(a.x); o[1] = (short)f2bf(a.y);
    o[2] = (short)f2bf(a.z); o[3] = (short)f2bf(a.w);
    o[4] = (short)f2bf(b.x); o[5] = (short)f2bf(b.y);
    o[6] = (short)f2bf(b.z); o[7] = (short)f2bf(b.w);
    return o;
}

// exp 4 floats, accumulate into sacc, pack bf16x4, 8B LDS store
__device__ __forceinline__ void expstore4(const float4& a,
                                          unsigned short* dst, float& sacc) {
    const float s0 = __expf(a.x), s1 = __expf(a.y), s2 = __expf(a.z), s3 = __expf(a.w);
    sacc += (s0 + s1) + (s2 + s3);
    bf16x4 o;
    o[0] = (short)f2bf(s0); o[1] = (short)f2bf(s1);
    o[2] = (short)f2bf(s2); o[3] = (short)f2bf(s3);
    *(bf16x4*)dst = o;
}

// ---------------------------------------------------------------------------
// Kernel 1: V[b,o,n] = bf16( sum_c W[o,c]*X[b,c,n] + bias[o] )
// (unchanged — will re-examine once attn is off the critical path)
// ---------------------------------------------------------------------------
__global__ __launch_bounds__(256) void value_gemm(
    const float* __restrict__ X, const float* __restrict__ W,
    const float* __restrict__ bias, unsigned short* __restrict__ Vout)
{
    __shared__ float Xs[256][33];   // [k][n] tile, +1 pad on 32

    const int t = threadIdx.x;
    const int b  = blockIdx.x >> 7;
    const int n0 = (blockIdx.x & 127) << 5;
    const int wave = t >> 6, lane = t & 63;
    const int lrow = lane & 15, lq = lane >> 4;

    const float* Xb = X + (size_t)b * Cc * Nn + n0;

    {
        const int r0 = t >> 3, c4 = (t & 7) << 2;
        #pragma unroll
        for (int i = 0; i < 8; ++i) {
            const int r = r0 + i * 32;
            const float4 v = *(const float4*)(Xb + (size_t)r * Nn + c4);
            Xs[r][c4 + 0] = v.x; Xs[r][c4 + 1] = v.y;
            Xs[r][c4 + 2] = v.z; Xs[r][c4 + 3] = v.w;
        }
    }
    __syncthreads();

    f32x4 acc[4][2] = {};

    #pragma unroll 2
    for (int k0 = 0; k0 < Cc; k0 += 32) {
        bf16x8 af[4];
        #pragma unroll
        for (int ci = 0; ci < 4; ++ci) {
            const float* wp = W + (size_t)(wave * 64 + ci * 16 + lrow) * Cc + k0 + lq * 8;
            af[ci] = pack2(*(const float4*)wp, *(const float4*)(wp + 4));
        }
        bf16x8 bp[2];
        #pragma unroll
        for (int mi = 0; mi < 2; ++mi) {
            const int n = mi * 16 + lrow;
            bf16x8 o;
            #pragma unroll
            for (int j = 0; j < 8; ++j) o[j] = (short)f2bf(Xs[k0 + lq * 8 + j][n]);
            bp[mi] = o;
        }
        #pragma unroll
        for (int ci = 0; ci < 4; ++ci)
            #pragma unroll
            for (int mi = 0; mi < 2; ++mi)
                acc[ci][mi] = __builtin_amdgcn_mfma_f32_16x16x32_bf16(
                    af[ci], bp[mi], acc[ci][mi], 0, 0, 0);
    }

    #pragma unroll
    for (int ci = 0; ci < 4; ++ci) {
        #pragma unroll
        for (int rr = 0; rr < 4; ++rr) {
            const int o = wave * 64 + ci * 16 + lq * 4 + rr;
            const float bo = bias[o];
            #pragma unroll
            for (int mi = 0; mi < 2; ++mi) {
                const int n = n0 + mi * 16 + lrow;
                Vout[((size_t)(b * Cc + o)) * Nn + n] = f2bf(acc[ci][mi][rr] + bo);
            }
        }
    }
}

// ---------------------------------------------------------------------------
// Kernel 2 v4: low-VGPR wave decomposition so prefetch survives regalloc.
// 32-row m-tiles, grid 512, block 512 (8 waves). Wave w owns EXCLUSIVE
// c-slice [w*32, w*32+32) x all 32 m rows:
//   V frags 4/buffer (32 VGPR double-buffered), acc 4xf32x4 (16 VGPR),
//   E prefetch 1 float4/thread/step x2 (8 VGPR)  -> ~100 VGPR total.
// __launch_bounds__(512,4): cap 128 VGPR -> 2 blocks/CU (stall decorrelation).
// XCD map: b=(blk&7)>>1 -> co-resident blocks on a CU share a batch's V
// (L1/L2 hits); each batch pinned to 2 XCDs.
// exp once per element -> Bexp bf16 LDS double buffer (round-2-verified
// swizzle). ONE LDS-only barrier per K-step; V/E loads in flight across it.
// ---------------------------------------------------------------------------
__global__ __launch_bounds__(512, 4) void attn_gemm(
    const unsigned short* __restrict__ V, const float* __restrict__ E,
    const float* __restrict__ X, const float* __restrict__ gamma,
    float* __restrict__ Out)
{
    __shared__ unsigned short Bexp[2][32 * 64];  // exp(E) [m][k] bf16, swizzled
    __shared__ float sum_lds[32];

    const int t = threadIdx.x;
    const int wave = t >> 6, lane = t & 63;
    const int lrow = lane & 15, lq = lane >> 4;
    const int l7 = lrow & 7;
    const int blk = blockIdx.x;
    const int b  = (blk & 7) >> 1;                       // batch -> XCD pair
    const int m0 = (((blk >> 3) << 1) | (blk & 1)) << 5; // 32-row m-tile

    // E ownership: thread owns row erow (0..31), 4 floats at col eg*4
    const int erow = t >> 4, eg = t & 15;
    const float* ep = E + (size_t)b * NN2 + (size_t)(m0 + erow) * Nn + eg * 4;
    // Bexp slot (round-2-verified): erow*64 + (((eg>>1)^(erow&7))<<3) + (eg&1)*4
    const int ss = erow * 64 + (((eg >> 1) ^ (erow & 7)) << 3) + ((eg & 1) << 2);
    unsigned short* const bst0 = &Bexp[0][ss];
    unsigned short* const bst1 = &Bexp[1][ss];

    // V fragments: rows wave*32 + ci*16 + lrow, cols lq*8 (+k*64 + kk*32)
    const unsigned short* vbase = V + (size_t)(b * Cc + wave * 32) * Nn;
    int voff[2];
    voff[0] = lrow * Nn + lq * 8;
    voff[1] = (16 + lrow) * Nn + lq * 8;

    f32x4 acc[2][2] = {};   // [ci][mi]
    float sacc = 0.f;

    float4 eE0, eE1;        // E prefetch regs (distance 2 steps)
    bf16x8 vA[4], vB[4];    // V frags [kk*2+ci], ping-pong

    // ---- prologue ----
    eE0 = *(const float4*)(ep);        // E(0)
    eE1 = *(const float4*)(ep + 64);   // E(1)
    #pragma unroll
    for (int kk = 0; kk < 2; ++kk)
        #pragma unroll
        for (int ci = 0; ci < 2; ++ci)
            vA[kk * 2 + ci] = *(const bf16x8*)(vbase + voff[ci] + kk * 32);  // V(0)
    expstore4(eE0, bst0, sacc);        // Bexp[0] = expE(0)
    eE0 = *(const float4*)(ep + 128);  // E(2)
    LDSBAR();

    // ---- main loop: 32 iterations x 2 steps, one barrier per step ----
    for (int k = 0; k < 64; k += 2) {
        // ===== even step s=k: consume vA, Bexp[0] =====
        {
            bf16x8 bfr[2][2];   // [kk][mi]
            #pragma unroll
            for (int kk = 0; kk < 2; ++kk)
                #pragma unroll
                for (int mi = 0; mi < 2; ++mi) {
                    const int rm = mi * 16 + lrow;
                    bfr[kk][mi] = *(const bf16x8*)&Bexp[0][rm * 64 + (((kk * 4 + lq) ^ l7) << 3)];
                }
            const int kv = (k + 1) << 6;                 // V(k+1)
            #pragma unroll
            for (int kk = 0; kk < 2; ++kk)
                #pragma unroll
                for (int ci = 0; ci < 2; ++ci)
                    vB[kk * 2 + ci] = *(const bf16x8*)(vbase + voff[ci] + kv + kk * 32);
            expstore4(eE1, bst1, sacc);                  // Bexp[1] = expE(k+1)
            eE1 = *(const float4*)(ep + (((k + 3) & 63) << 6));   // E(k+3)
            __builtin_amdgcn_s_setprio(1);
            #pragma unroll
            for (int ci = 0; ci < 2; ++ci)
                #pragma unroll
                for (int mi = 0; mi < 2; ++mi)
                    #pragma unroll
                    for (int kk = 0; kk < 2; ++kk)
                        acc[ci][mi] = __builtin_amdgcn_mfma_f32_16x16x32_bf16(
                            vA[kk * 2 + ci], bfr[kk][mi], acc[ci][mi], 0, 0, 0);
            __builtin_amdgcn_s_setprio(0);
            LDSBAR();
        }
        // ===== odd step s=k+1: consume vB, Bexp[1] =====
        {
            bf16x8 bfr[2][2];
            #pragma unroll
            for (int kk = 0; kk < 2; ++kk)
                #pragma unroll
                for (int mi = 0; mi < 2; ++mi) {
                    const int rm = mi * 16 + lrow;
                    bfr[kk][mi] = *(const bf16x8*)&Bexp[1][rm * 64 + (((kk * 4 + lq) ^ l7) << 3)];
                }
            const int kv = ((k + 2) & 63) << 6;          // V(k+2) (tail wraps)
            #pragma unroll
            for (int kk = 0; kk < 2; ++kk)
                #pragma unroll
                for (int ci = 0; ci < 2; ++ci)
                    vA[kk * 2 + ci] = *(const bf16x8*)(vbase + voff[ci] + kv + kk * 32);
            if (k != 62) {                               // no step 64: protect sacc
                expstore4(eE0, bst0, sacc);              // Bexp[0] = expE(k+2)
                eE0 = *(const float4*)(ep + (((k + 4) & 63) << 6));  // E(k+4)
            }
            __builtin_amdgcn_s_setprio(1);
            #pragma unroll
            for (int ci = 0; ci < 2; ++ci)
                #pragma unroll
                for (int mi = 0; mi < 2; ++mi)
                    #pragma unroll
                    for (int kk = 0; kk < 2; ++kk)
                        acc[ci][mi] = __builtin_amdgcn_mfma_f32_16x16x32_bf16(
                            vB[kk * 2 + ci], bfr[kk][mi], acc[ci][mi], 0, 0, 0);
            __builtin_amdgcn_s_setprio(0);
            LDSBAR();
        }
    }

    // ---- softmax denominators: 16 owner-threads per m-row, same wave ----
    {
        float s = sacc;
        s += __shfl_xor(s, 1);
        s += __shfl_xor(s, 2);
        s += __shfl_xor(s, 4);
        s += __shfl_xor(s, 8);
        if (eg == 0) sum_lds[erow] = s;
    }
    __syncthreads();

    // ---- epilogue ----
    const float g = gamma[0];
    #pragma unroll
    for (int mi = 0; mi < 2; ++mi) {
        const int mloc = mi * 16 + lrow;
        const float scale = g / sum_lds[mloc];
        const int m = m0 + mloc;
        #pragma unroll
        for (int ci = 0; ci < 2; ++ci) {
            #pragma unroll
            for (int rr = 0; rr < 4; ++rr) {
                const int c = wave * 32 + ci * 16 + lq * 4 + rr;
                const size_t off = ((size_t)(b * Cc + c)) * Nn + m;
                Out[off] = scale * acc[ci][mi][rr] + 2.0f * X[off];
            }
        }
    }
}

extern "C" void kernel_launch(void* const* d_in, const int* in_sizes, int n_in,
                              void* d_out, int out_size, void* d_ws, size_t ws_size,
                              hipStream_t stream) {
    const float* energy  = (const float*)d_in[0];  // [4,4096,4096]
    const float* x       = (const float*)d_in[1];  // [4,256,64,64]
    const float* value_w = (const float*)d_in[2];  // [256,256]
    const float* value_b = (const float*)d_in[3];  // [256]
    const float* gamma   = (const float*)d_in[4];  // [1]
    float* out = (float*)d_out;
    unsigned short* Vws = (unsigned short*)d_ws;   // 4*256*4096 bf16 = 8 MB

    value_gemm<<<512, 256, 0, stream>>>(x, value_w, value_b, Vws);
    attn_gemm<<<512, 512, 0, stream>>>(Vws, energy, x, gamma, out);
}